// Round 11
// baseline (105.614 us; speedup 1.0000x reference)
//
#include <hip/hip_runtime.h>

// FlowNetC correlation, B=8 C=256 H=64 W=128, 9x9 grid.
// out[b,dy*9+dx,h,w] = (1/256) * sum_c in1[b,c,h,w]*in2[b,c,h+dy-4,w+dx-4]
// (in2 zero-padded by 4 in h,w).
//
// Block = (b,h,dy) -> ONE in2 row. 4608 blocks x 256 thr (4 waves).
// Thread = (q:16 w-octs) x (cslo:4); wave w owns channels 16p+4w+cslo.
// Wave-private staging via global_load_lds dwordx4, no barriers in main loop.
// R11 (single change vs R10-95us): prefetch depth 1 -> 3. NBUF=4 LDS buffers
// (66.5 KB), period-4 static rotation, VMCNT(12) keeps 3 phases x 4 DMA ops
// in flight across every COMPUTE. Theory: R5/R8/R10 all sustain only
// ~22-24 B/cyc/CU through the global->LDS path at depth 1 (instr count,
// line density, layout all falsified); m201's counted-vmcnt 3-deep pipeline
// sustains ~80 B/cyc/CU on the same path -> depth is the lever. Costs zero
// registers (v1 lives in LDS since R10); LDS-limited 2 blocks/CU is the
// m201 trade (ILP for TLP).
// Tripwires: WRITE_SIZE == 20736 KB (spill), passed (R9 overwrite race ->
// LGKM0 fence after each COMPUTE before that buffer is re-staged).

#define AS1 __attribute__((address_space(1)))
#define AS3 __attribute__((address_space(3)))

namespace {

constexpr int Cc = 256, Hh = 64, Ww = 128;
constexpr int HW = Hh * Ww;   // 8192
constexpr int ND = 81;
constexpr int PBUF = 1040;    // per wave/buffer: 520 in2 (512+4zero+pad) + 512 v1 + 8 pad
constexpr int NBUF = 4;       // quad-buffer -> depth-3 prefetch
constexpr int WREG = NBUF * PBUF;  // 4160 floats per wave

__device__ __forceinline__ void async16(const float* g, float* l) {
  __builtin_amdgcn_global_load_lds((const AS1 unsigned int*)g,
                                   (AS3 unsigned int*)l, 16, 0, 0);
}

__global__ __launch_bounds__(256, 3) void corr_kernel(
    const float* __restrict__ in1, const float* __restrict__ in2,
    float* __restrict__ out) {
  __shared__ __align__(16) float lds[4 * WREG];  // 16640 f = 66.56 KB

  const int tid = threadIdx.x;
  const int w = tid >> 6;
  const int lane = tid & 63;
  const int q = lane & 15;
  const int cslo = lane >> 4;

  // XCD swizzle: dispatch i -> XCD i%8; XCD x gets batch x; 9 dy-siblings of
  // one (b,h) are consecutive -> co-resident on one XCD, sharing rows in L2.
  const int bid0 = blockIdx.x;
  const int nb = (bid0 & 7) * 576 + (bid0 >> 3);
  const int b = nb / 576;
  const int rem = nb - b * 576;
  const int h = rem / 9;
  const int dy = rem - h * 9;
  const int row2 = h + dy - 4;

  float* outbase = out + (((size_t)b * ND + (size_t)dy * 9) * Hh + h) * Ww;

  if ((unsigned)row2 >= (unsigned)Hh) {  // dy shifts row out of range -> zeros
    if (tid < 144) {
      const int dx = tid >> 4, qq = tid & 15;
      const float4 z = make_float4(0.f, 0.f, 0.f, 0.f);
      *(float4*)(outbase + (size_t)dx * HW + 8 * qq) = z;
      *(float4*)(outbase + (size_t)dx * HW + 8 * qq + 4) = z;
    }
    return;
  }

  const int wb = w * WREG;
  // zero the 16-B zero-slot of each of the 4 phase buffers (floats 512..515)
  if (lane < 16) lds[wb + (lane >> 2) * PBUF + 512 + (lane & 3)] = 0.0f;

  // ---- in2 staging source mapping (inverse of the [odds|evens]+rot layout) ----
  // dest slot s (16B units) in [0,128): c = s>>5, v = s&31, vp = (v-2c)&31,
  // quad g = vp<16 ? 2*vp+1 : 2*(vp-16). instr k covers slots 64k + lane.
  int srcA, srcB;
  {
    const int s0 = lane, c0 = s0 >> 5, v0 = s0 & 31;
    const int vp0 = (v0 - 2 * c0) & 31;
    const int g0 = (vp0 < 16) ? (2 * vp0 + 1) : (2 * (vp0 - 16));
    srcA = (4 * w + c0) * HW + 4 * g0;
    const int s1 = 64 + lane, c1 = s1 >> 5, v1_ = s1 & 31;
    const int vp1 = (v1_ - 2 * c1) & 31;
    const int g1 = (vp1 < 16) ? (2 * vp1 + 1) : (2 * (vp1 - 16));
    srcB = (4 * w + c1) * HW + 4 * g1;
  }
  // ---- v1 staging source mapping (dense, linear) ----
  // instr k: lane l -> dest float 520 + 256k + 4l ; holds ch (4w + 2k + (l>>5)),
  // x = (4l)&127.
  const int v1srcA = (4 * w + (lane >> 5)) * HW + ((4 * lane) & 127);
  const int v1srcB = (4 * w + 2 + (lane >> 5)) * HW + ((4 * lane) & 127);

  // ---- per-thread in2 window read offsets (floats, within phase buffer) ----
  // window t[k] = x 8q-4+k; quads {q-1, 16+q, q, 17+q} rotated by 2*cslo;
  // q==0 first / q==15 last quad -> zero slot (float 512).
  const int ro0 = (q == 0) ? 512 : (cslo * 32 + ((q - 1 + 2 * cslo) & 31)) * 4;
  const int ro1 = (cslo * 32 + ((16 + q + 2 * cslo) & 31)) * 4;
  const int ro2 = (cslo * 32 + ((q + 2 * cslo) & 31)) * 4;
  const int ro3 = (q == 15) ? 512 : (cslo * 32 + ((17 + q + 2 * cslo) & 31)) * 4;
  // v1 read offset: floats 520 + cslo*128 + 8q (2x b128)
  const int vro = 520 + cslo * 128 + 8 * q;

  const float* in2row = in2 + ((size_t)b * Cc * Hh + row2) * Ww;
  const float* in1row = in1 + ((size_t)b * Cc * Hh + h) * Ww;

#define STAGE(P, BI)                                                   \
  {                                                                    \
    const float* s2_ = in2row + (size_t)(16 * (P)) * HW;               \
    const float* s1_ = in1row + (size_t)(16 * (P)) * HW;               \
    async16(s2_ + srcA, &lds[wb + (BI) * PBUF]);                       \
    async16(s2_ + srcB, &lds[wb + (BI) * PBUF + 256]);                 \
    async16(s1_ + v1srcA, &lds[wb + (BI) * PBUF + 520]);               \
    async16(s1_ + v1srcB, &lds[wb + (BI) * PBUF + 776]);               \
  }

#define COMPUTE(BI)                                                      \
  {                                                                      \
    const int bb_ = wb + (BI) * PBUF;                                    \
    const float4 A_ = *(const float4*)&lds[bb_ + ro0]; /* t0..3  */      \
    const float4 B_ = *(const float4*)&lds[bb_ + ro1]; /* t4..7  */      \
    const float4 C_ = *(const float4*)&lds[bb_ + ro2]; /* t8..11 */      \
    const float4 D_ = *(const float4*)&lds[bb_ + ro3]; /* t12..15*/      \
    const float4 Va_ = *(const float4*)&lds[bb_ + vro];                  \
    const float4 Vb_ = *(const float4*)&lds[bb_ + vro + 4];              \
    const float t_[16] = {A_.x, A_.y, A_.z, A_.w, B_.x, B_.y, B_.z, B_.w,\
                          C_.x, C_.y, C_.z, C_.w, D_.x, D_.y, D_.z, D_.w};\
    const float v_[8] = {Va_.x, Va_.y, Va_.z, Va_.w,                     \
                         Vb_.x, Vb_.y, Vb_.z, Vb_.w};                    \
    _Pragma("unroll") for (int dx_ = 0; dx_ < 9; ++dx_)                  \
      _Pragma("unroll") for (int px_ = 0; px_ < 8; ++px_)                \
        acc[px_][dx_] = fmaf(v_[px_], t_[px_ + dx_], acc[px_][dx_]);     \
  }

#define VMCNT(N) asm volatile("s_waitcnt vmcnt(" #N ")" ::: "memory")
// Read-retire fence: all ds_reads of the preceding COMPUTE have returned
// before a later STAGE overwrites that buffer (DMA LDS-writes are not
// ordered vs queued ds_reads -- R9 failure). sched_barrier pins codegen.
#define LGKM0                                             \
  asm volatile("s_waitcnt lgkmcnt(0)" ::: "memory");      \
  __builtin_amdgcn_sched_barrier(0)

  float acc[8][9];
#pragma unroll
  for (int px = 0; px < 8; ++px)
#pragma unroll
    for (int dx = 0; dx < 9; ++dx) acc[px][dx] = 0.0f;

  STAGE(0, 0);
  STAGE(1, 1);
  STAGE(2, 2);

  // phase p: issue STAGE(p+3) -> wait vmcnt(12) (retires stage(p); keeps
  // p+1,p+2,p+3 = 12 ops in flight) -> COMPUTE(p) -> LGKM0 (buf safe to
  // re-stage next phase). Buffer = p&3, all static via period-4 unroll.
#pragma unroll 1
  for (int pp = 0; pp < 12; pp += 4) {
    STAGE(pp + 3, 3); VMCNT(12); COMPUTE(0); LGKM0;
    STAGE(pp + 4, 0); VMCNT(12); COMPUTE(1); LGKM0;
    STAGE(pp + 5, 1); VMCNT(12); COMPUTE(2); LGKM0;
    STAGE(pp + 6, 2); VMCNT(12); COMPUTE(3); LGKM0;
  }
  // tail: phases 12..15 (stages 13,14 issued in last loop iter; 15 here)
  STAGE(15, 3); VMCNT(12); COMPUTE(0); LGKM0;  // phase 12
  VMCNT(8);  COMPUTE(1);                        // phase 13
  VMCNT(4);  COMPUTE(2);                        // phase 14
  VMCNT(0);  COMPUTE(3);                        // phase 15

  // reduce the 4 cslo slices within each wave (lanes q, q+16, q+32, q+48)
#pragma unroll
  for (int px = 0; px < 8; ++px)
#pragma unroll
    for (int dx = 0; dx < 9; ++dx) {
      float v = acc[px][dx];
      v += __shfl_xor(v, 16, 64);
      v += __shfl_xor(v, 32, 64);
      acc[px][dx] = v;
    }

  __syncthreads();  // all waves done with staging region before overwrite
  if (cslo == 0) {  // wave partial: lds[((w*16+q)*9+dx)*8+px]
    const int pb = (w * 16 + q) * 72;
#pragma unroll
    for (int dx = 0; dx < 9; ++dx) {
      *(float4*)&lds[pb + dx * 8] =
          make_float4(acc[0][dx], acc[1][dx], acc[2][dx], acc[3][dx]);
      *(float4*)&lds[pb + dx * 8 + 4] =
          make_float4(acc[4][dx], acc[5][dx], acc[6][dx], acc[7][dx]);
    }
  }
  __syncthreads();

  if (tid < 144) {  // sum 4 wave-partials, scale, store
    const int dx = tid >> 4, qq = tid & 15;
    const float s = 1.0f / 256.0f;
    float r[8];
#pragma unroll
    for (int px = 0; px < 8; ++px) r[px] = 0.0f;
#pragma unroll
    for (int w4 = 0; w4 < 4; ++w4) {
      const int pb = ((w4 * 16 + qq) * 9 + dx) * 8;
      const float4 lo = *(const float4*)&lds[pb];
      const float4 hi = *(const float4*)&lds[pb + 4];
      r[0] += lo.x; r[1] += lo.y; r[2] += lo.z; r[3] += lo.w;
      r[4] += hi.x; r[5] += hi.y; r[6] += hi.z; r[7] += hi.w;
    }
    *(float4*)(outbase + (size_t)dx * HW + 8 * qq) =
        make_float4(r[0] * s, r[1] * s, r[2] * s, r[3] * s);
    *(float4*)(outbase + (size_t)dx * HW + 8 * qq + 4) =
        make_float4(r[4] * s, r[5] * s, r[6] * s, r[7] * s);
  }
}

}  // namespace

extern "C" void kernel_launch(void* const* d_in, const int* in_sizes, int n_in,
                              void* d_out, int out_size, void* d_ws,
                              size_t ws_size, hipStream_t stream) {
  (void)in_sizes; (void)n_in; (void)out_size; (void)d_ws; (void)ws_size;
  const float* in1 = (const float*)d_in[0];
  const float* in2 = (const float*)d_in[1];
  float* outp = (float*)d_out;
  corr_kernel<<<4608, 256, 0, stream>>>(in1, in2, outp);
}

// Round 12
// 94.883 us; speedup vs baseline: 1.1131x; 1.1131x over previous
//
#include <hip/hip_runtime.h>

// FlowNetC correlation, B=8 C=256 H=64 W=128, 9x9 grid.
// out[b,dy*9+dx,h,w] = (1/256) * sum_c in1[b,c,h,w]*in2[b,c,h+dy-4,w+dx-4]
// (in2 zero-padded by 4 in h,w).
//
// Block = (b,h,dy) -> ONE in2 row. 4608 blocks x 256 thr (4 waves).
// Thread = (q:16 w-octs) x (cslo:4); wave w owns channels 16p+4w+cslo.
// Wave-private staging, no barriers in main loop; depth-1, vmcnt(4).
// R12 (single change vs R10-95us): DENSE LINEAR staging. All 4 STAGE ops are
// contiguous 1KB (lane l <- base+16l, 16 lines/op). Theory v4: the
// global->LDS path is REQUEST-rate limited (~1 segment/cyc/CU); the old
// parity-deinterleaved source scattered 64 lanes to 64 discontiguous 16B
// segments/op (~2-3K req/CU-phase ~= the observed 2250cyc phase). Falsified
// so far: instr count (R8), line density (R10), per-wave depth (R11), reg
// pipelining (R6/R7). Cost accepted: linear [c][x] rows -> window b128 reads
// ~2x the 8-cyc floor (16 lanes/bank-group) ~= +500 cyc/phase, << the
// ~1500-2000 cyc DMA saving if v4 holds.
// Tripwires: WRITE_SIZE == 20736 KB (spill); LGKM0 fence after each COMPUTE
// (R9 overwrite race).

#define AS1 __attribute__((address_space(1)))
#define AS3 __attribute__((address_space(3)))

namespace {

constexpr int Cc = 256, Hh = 64, Ww = 128;
constexpr int HW = Hh * Ww;   // 8192
constexpr int ND = 81;
constexpr int PBUF = 1040;    // per wave/buffer: 512 in2 + 4 zero + pad | 512 v1 + pad
constexpr int WREG = 2 * PBUF;  // 2080 floats per wave (double-buffered)

__device__ __forceinline__ void async16(const float* g, float* l) {
  __builtin_amdgcn_global_load_lds((const AS1 unsigned int*)g,
                                   (AS3 unsigned int*)l, 16, 0, 0);
}

__global__ __launch_bounds__(256, 3) void corr_kernel(
    const float* __restrict__ in1, const float* __restrict__ in2,
    float* __restrict__ out) {
  __shared__ __align__(16) float lds[8320];  // 4 waves x 2080; reduce reuses [0,4608)

  const int tid = threadIdx.x;
  const int w = tid >> 6;
  const int lane = tid & 63;
  const int q = lane & 15;
  const int cslo = lane >> 4;

  // XCD swizzle: dispatch i -> XCD i%8; XCD x gets batch x; 9 dy-siblings of
  // one (b,h) are consecutive -> co-resident on one XCD, sharing rows in L2.
  const int bid0 = blockIdx.x;
  const int nb = (bid0 & 7) * 576 + (bid0 >> 3);
  const int b = nb / 576;
  const int rem = nb - b * 576;
  const int h = rem / 9;
  const int dy = rem - h * 9;
  const int row2 = h + dy - 4;

  float* outbase = out + (((size_t)b * ND + (size_t)dy * 9) * Hh + h) * Ww;

  if ((unsigned)row2 >= (unsigned)Hh) {  // dy shifts row out of range -> zeros
    if (tid < 144) {
      const int dx = tid >> 4, qq = tid & 15;
      const float4 z = make_float4(0.f, 0.f, 0.f, 0.f);
      *(float4*)(outbase + (size_t)dx * HW + 8 * qq) = z;
      *(float4*)(outbase + (size_t)dx * HW + 8 * qq + 4) = z;
    }
    return;
  }

  const int wb = w * WREG;
  // zero the 16-B zero-slot of each phase buffer (floats 512..515)
  if (lane < 8) lds[wb + (lane >> 2) * PBUF + 512 + (lane & 3)] = 0.0f;

  // ---- dense staging source mappings (dest linear: float 4*lane within op) ----
  // in2 op k: dest float 256k+4l holds channel (4w+2k+(l>>5)), x = 4*(l&31).
  const int srcA = (4 * w + (lane >> 5)) * HW + 4 * (lane & 31);
  const int srcB = srcA + 2 * HW;
  // v1 op k: dest float 520+256k+4l, same mapping.
  const int v1srcA = srcA;
  const int v1srcB = srcB;

  // ---- per-thread in2 window read offsets (floats, within phase buffer) ----
  // linear row: channel cslo at floats [128*cslo, 128*cslo+128).
  // window t[k] = x 8q-4+k: quads at 8q-4, 8q, 8q+4, 8q+8.
  // q==0 first / q==15 last quad are out of row -> zero slot (float 512).
  const int ro0 = (q == 0) ? 512 : (128 * cslo + 8 * q - 4);
  const int ro1 = 128 * cslo + 8 * q;
  const int ro2 = 128 * cslo + 8 * q + 4;
  const int ro3 = (q == 15) ? 512 : (128 * cslo + 8 * q + 8);
  // v1 read offset: floats 520 + cslo*128 + 8q (2x b128)
  const int vro = 520 + cslo * 128 + 8 * q;

  const float* in2row = in2 + ((size_t)b * Cc * Hh + row2) * Ww;
  const float* in1row = in1 + ((size_t)b * Cc * Hh + h) * Ww;

#define STAGE(P, BI)                                                   \
  {                                                                    \
    const float* s2_ = in2row + (size_t)(16 * (P)) * HW;               \
    const float* s1_ = in1row + (size_t)(16 * (P)) * HW;               \
    async16(s2_ + srcA, &lds[wb + (BI) * PBUF]);                       \
    async16(s2_ + srcB, &lds[wb + (BI) * PBUF + 256]);                 \
    async16(s1_ + v1srcA, &lds[wb + (BI) * PBUF + 520]);               \
    async16(s1_ + v1srcB, &lds[wb + (BI) * PBUF + 776]);               \
  }

#define COMPUTE(BI)                                                      \
  {                                                                      \
    const int bb_ = wb + (BI) * PBUF;                                    \
    const float4 A_ = *(const float4*)&lds[bb_ + ro0]; /* t0..3  */      \
    const float4 B_ = *(const float4*)&lds[bb_ + ro1]; /* t4..7  */      \
    const float4 C_ = *(const float4*)&lds[bb_ + ro2]; /* t8..11 */      \
    const float4 D_ = *(const float4*)&lds[bb_ + ro3]; /* t12..15*/      \
    const float4 Va_ = *(const float4*)&lds[bb_ + vro];                  \
    const float4 Vb_ = *(const float4*)&lds[bb_ + vro + 4];              \
    const float t_[16] = {A_.x, A_.y, A_.z, A_.w, B_.x, B_.y, B_.z, B_.w,\
                          C_.x, C_.y, C_.z, C_.w, D_.x, D_.y, D_.z, D_.w};\
    const float v_[8] = {Va_.x, Va_.y, Va_.z, Va_.w,                     \
                         Vb_.x, Vb_.y, Vb_.z, Vb_.w};                    \
    _Pragma("unroll") for (int dx_ = 0; dx_ < 9; ++dx_)                  \
      _Pragma("unroll") for (int px_ = 0; px_ < 8; ++px_)                \
        acc[px_][dx_] = fmaf(v_[px_], t_[px_ + dx_], acc[px_][dx_]);     \
  }

#define VMCNT(N) asm volatile("s_waitcnt vmcnt(" #N ")" ::: "memory")
// Read-retire fence: all ds_reads of the preceding COMPUTE have returned
// before a later STAGE overwrites that buffer (DMA LDS-writes are not
// ordered vs queued ds_reads -- R9 failure). sched_barrier pins codegen.
#define LGKM0                                             \
  asm volatile("s_waitcnt lgkmcnt(0)" ::: "memory");      \
  __builtin_amdgcn_sched_barrier(0)

  float acc[8][9];
#pragma unroll
  for (int px = 0; px < 8; ++px)
#pragma unroll
    for (int dx = 0; dx < 9; ++dx) acc[px][dx] = 0.0f;

  STAGE(0, 0);

#pragma unroll 1
  for (int pp = 0; pp < 16; pp += 2) {
    STAGE(pp + 1, 1);
    VMCNT(4);  // drain phase pp's 4 ops; keep pp+1's 4 in flight
    COMPUTE(0);
    LGKM0;     // buf0 reads retired before re-staging buf0
    if (pp + 2 < 16) {
      STAGE(pp + 2, 0);
      VMCNT(4);
    } else {
      VMCNT(0);
    }
    COMPUTE(1);
    LGKM0;     // buf1 reads retired before next iteration re-stages buf1
  }

  // reduce the 4 cslo slices within each wave (lanes q, q+16, q+32, q+48)
#pragma unroll
  for (int px = 0; px < 8; ++px)
#pragma unroll
    for (int dx = 0; dx < 9; ++dx) {
      float v = acc[px][dx];
      v += __shfl_xor(v, 16, 64);
      v += __shfl_xor(v, 32, 64);
      acc[px][dx] = v;
    }

  __syncthreads();  // all waves done with staging region before overwrite
  if (cslo == 0) {  // wave partial: lds[((w*16+q)*9+dx)*8+px]
    const int pb = (w * 16 + q) * 72;
#pragma unroll
    for (int dx = 0; dx < 9; ++dx) {
      *(float4*)&lds[pb + dx * 8] =
          make_float4(acc[0][dx], acc[1][dx], acc[2][dx], acc[3][dx]);
      *(float4*)&lds[pb + dx * 8 + 4] =
          make_float4(acc[4][dx], acc[5][dx], acc[6][dx], acc[7][dx]);
    }
  }
  __syncthreads();

  if (tid < 144) {  // sum 4 wave-partials, scale, store
    const int dx = tid >> 4, qq = tid & 15;
    const float s = 1.0f / 256.0f;
    float r[8];
#pragma unroll
    for (int px = 0; px < 8; ++px) r[px] = 0.0f;
#pragma unroll
    for (int w4 = 0; w4 < 4; ++w4) {
      const int pb = ((w4 * 16 + qq) * 9 + dx) * 8;
      const float4 lo = *(const float4*)&lds[pb];
      const float4 hi = *(const float4*)&lds[pb + 4];
      r[0] += lo.x; r[1] += lo.y; r[2] += lo.z; r[3] += lo.w;
      r[4] += hi.x; r[5] += hi.y; r[6] += hi.z; r[7] += hi.w;
    }
    *(float4*)(outbase + (size_t)dx * HW + 8 * qq) =
        make_float4(r[0] * s, r[1] * s, r[2] * s, r[3] * s);
    *(float4*)(outbase + (size_t)dx * HW + 8 * qq + 4) =
        make_float4(r[4] * s, r[5] * s, r[6] * s, r[7] * s);
  }
}

}  // namespace

extern "C" void kernel_launch(void* const* d_in, const int* in_sizes, int n_in,
                              void* d_out, int out_size, void* d_ws,
                              size_t ws_size, hipStream_t stream) {
  (void)in_sizes; (void)n_in; (void)out_size; (void)d_ws; (void)ws_size;
  const float* in1 = (const float*)d_in[0];
  const float* in2 = (const float*)d_in[1];
  float* outp = (float*)d_out;
  corr_kernel<<<4608, 256, 0, stream>>>(in1, in2, outp);
}

// Round 13
// 92.385 us; speedup vs baseline: 1.1432x; 1.0270x over previous
//
#include <hip/hip_runtime.h>

// FlowNetC correlation, B=8 C=256 H=64 W=128, 9x9 grid.
// out[b,dy*9+dx,h,w] = (1/256) * sum_c in1[b,c,h,w]*in2[b,c,h+dy-4,w+dx-4]
// (in2 zero-padded by 4 in h,w).
//
// Block = (b,h,dy) -> ONE in2 row. 4608 blocks x 256 thr (4 waves).
// Thread = (q:16 w-octs) x (cslo:4); wave w owns 4 channels/phase.
// R13 (single structural change vs R12-95us): REG-STAGED staging (T14).
// The 4 global_load_lds become 4 global_load_dwordx4 -> VGPR + 4
// ds_write_b128 one phase-step later. Theory v5: the global->LDS DMA engine
// has a small per-CU queue capping it at ~22 B/cyc/CU regardless of issued
// depth (R8/R10/R11/R12 all flat at that rate); the normal vector-load path
// sustains 50-80 B/cyc/CU in GEMM reg-staging (m151). Bonus: vector loads go
// through L1 -- 3 co-resident dy-siblings read the IDENTICAL in1 row.
// Same-wave DS ops are ordered -> R9's DMA overwrite race vanishes; LGKM0
// fences dropped (compiler inserts exact waits from visible memory deps).
// Falsified: instr count (R8), line density (R10), per-wave DMA depth (R11),
// reg pipelining (R6/7), address scatter (R12).
// Tripwires: WRITE_SIZE == 20736 KB (spill); keep __launch_bounds__(256,3).

namespace {

constexpr int Cc = 256, Hh = 64, Ww = 128;
constexpr int HW = Hh * Ww;   // 8192
constexpr int ND = 81;
constexpr int PBUF = 1040;    // per wave/buffer: 512 in2 | 4 zero | pad | 512 v1 | pad
constexpr int WREG = 2 * PBUF;  // 2080 floats per wave (double-buffered)

__global__ __launch_bounds__(256, 3) void corr_kernel(
    const float* __restrict__ in1, const float* __restrict__ in2,
    float* __restrict__ out) {
  __shared__ __align__(16) float lds[8320];  // 4 waves x 2080; reduce reuses [0,4608)

  const int tid = threadIdx.x;
  const int w = tid >> 6;
  const int lane = tid & 63;
  const int q = lane & 15;
  const int cslo = lane >> 4;

  // XCD swizzle: dispatch i -> XCD i%8; XCD x gets batch x; 9 dy-siblings of
  // one (b,h) are consecutive -> co-resident on one XCD (often one CU),
  // sharing the in1 row (L1/L2) and overlapping in2 rows (L2).
  const int bid0 = blockIdx.x;
  const int nb = (bid0 & 7) * 576 + (bid0 >> 3);
  const int b = nb / 576;
  const int rem = nb - b * 576;
  const int h = rem / 9;
  const int dy = rem - h * 9;
  const int row2 = h + dy - 4;

  float* outbase = out + (((size_t)b * ND + (size_t)dy * 9) * Hh + h) * Ww;

  if ((unsigned)row2 >= (unsigned)Hh) {  // dy shifts row out of range -> zeros
    if (tid < 144) {
      const int dx = tid >> 4, qq = tid & 15;
      const float4 z = make_float4(0.f, 0.f, 0.f, 0.f);
      *(float4*)(outbase + (size_t)dx * HW + 8 * qq) = z;
      *(float4*)(outbase + (size_t)dx * HW + 8 * qq + 4) = z;
    }
    return;
  }

  const int wb = w * WREG;
  // zero the 16-B zero-slot of each phase buffer (floats 512..515)
  if (lane < 8) lds[wb + (lane >> 2) * PBUF + 512 + (lane & 3)] = 0.0f;

  // dense source mapping: op covers 4 channel-rows, lane l -> channel
  // (4w + base + (l>>5)), x = 4*(l&31); dest float 4*lane within region.
  const int srcA = (4 * w + (lane >> 5)) * HW + 4 * (lane & 31);
  const int srcB = srcA + 2 * HW;

  // per-thread in2 window read offsets (linear row, channel cslo):
  // window t[k] = x 8q-4+k: quads at 8q-4, 8q, 8q+4, 8q+8; edges -> zero slot.
  const int ro0 = (q == 0) ? 512 : (128 * cslo + 8 * q - 4);
  const int ro1 = 128 * cslo + 8 * q;
  const int ro2 = 128 * cslo + 8 * q + 4;
  const int ro3 = (q == 15) ? 512 : (128 * cslo + 8 * q + 8);
  const int vro = 520 + cslo * 128 + 8 * q;  // v1: 2x b128

  const float* in2row = in2 + ((size_t)b * Cc * Hh + row2) * Ww;
  const float* in1row = in1 + ((size_t)b * Cc * Hh + h) * Ww;

#define STAGE_LOAD(P)                                                  \
  {                                                                    \
    const float* s2_ = in2row + (size_t)(16 * (P)) * HW;               \
    const float* s1_ = in1row + (size_t)(16 * (P)) * HW;               \
    g2a = *(const float4*)(s2_ + srcA);                                \
    g2b = *(const float4*)(s2_ + srcB);                                \
    g1a = *(const float4*)(s1_ + srcA);                                \
    g1b = *(const float4*)(s1_ + srcB);                                \
  }

#define STAGE_WRITE(BI)                                                \
  {                                                                    \
    float* d_ = &lds[wb + (BI) * PBUF + 4 * lane];                     \
    *(float4*)(d_) = g2a;                                              \
    *(float4*)(d_ + 256) = g2b;                                        \
    *(float4*)(d_ + 520) = g1a;                                        \
    *(float4*)(d_ + 776) = g1b;                                        \
  }

#define COMPUTE(BI)                                                      \
  {                                                                      \
    const int bb_ = wb + (BI) * PBUF;                                    \
    const float4 A_ = *(const float4*)&lds[bb_ + ro0]; /* t0..3  */      \
    const float4 B_ = *(const float4*)&lds[bb_ + ro1]; /* t4..7  */      \
    const float4 C_ = *(const float4*)&lds[bb_ + ro2]; /* t8..11 */      \
    const float4 D_ = *(const float4*)&lds[bb_ + ro3]; /* t12..15*/      \
    const float4 Va_ = *(const float4*)&lds[bb_ + vro];                  \
    const float4 Vb_ = *(const float4*)&lds[bb_ + vro + 4];              \
    const float t_[16] = {A_.x, A_.y, A_.z, A_.w, B_.x, B_.y, B_.z, B_.w,\
                          C_.x, C_.y, C_.z, C_.w, D_.x, D_.y, D_.z, D_.w};\
    const float v_[8] = {Va_.x, Va_.y, Va_.z, Va_.w,                     \
                         Vb_.x, Vb_.y, Vb_.z, Vb_.w};                    \
    _Pragma("unroll") for (int dx_ = 0; dx_ < 9; ++dx_)                  \
      _Pragma("unroll") for (int px_ = 0; px_ < 8; ++px_)                \
        acc[px_][dx_] = fmaf(v_[px_], t_[px_ + dx_], acc[px_][dx_]);     \
  }

#define SBAR __builtin_amdgcn_sched_barrier(0)

  float acc[8][9];
#pragma unroll
  for (int px = 0; px < 8; ++px)
#pragma unroll
    for (int dx = 0; dx < 9; ++dx) acc[px][dx] = 0.0f;

  float4 g2a, g2b, g1a, g1b;  // staging registers (one step in flight)

  STAGE_LOAD(0);
  STAGE_WRITE(0);   // compiler inserts vmcnt before the ds_writes
  STAGE_LOAD(1);

  // step p: WRITE(p+1) [drains loads issued one step ago], LOAD(p+2)
  // [covered by this step's compute], COMPUTE(p). Buffer = p&1, static.
#pragma unroll 1
  for (int pp = 0; pp < 14; pp += 2) {
    STAGE_WRITE(1); STAGE_LOAD(pp + 2); SBAR; COMPUTE(0);
    STAGE_WRITE(0); STAGE_LOAD(pp + 3); SBAR; COMPUTE(1);
  }
  STAGE_WRITE(1); SBAR;
  COMPUTE(0);  // phase 14
  COMPUTE(1);  // phase 15

  // reduce the 4 cslo slices within each wave (lanes q, q+16, q+32, q+48)
#pragma unroll
  for (int px = 0; px < 8; ++px)
#pragma unroll
    for (int dx = 0; dx < 9; ++dx) {
      float v = acc[px][dx];
      v += __shfl_xor(v, 16, 64);
      v += __shfl_xor(v, 32, 64);
      acc[px][dx] = v;
    }

  __syncthreads();  // all waves done with staging region before overwrite
  if (cslo == 0) {  // wave partial: lds[((w*16+q)*9+dx)*8+px]
    const int pb = (w * 16 + q) * 72;
#pragma unroll
    for (int dx = 0; dx < 9; ++dx) {
      *(float4*)&lds[pb + dx * 8] =
          make_float4(acc[0][dx], acc[1][dx], acc[2][dx], acc[3][dx]);
      *(float4*)&lds[pb + dx * 8 + 4] =
          make_float4(acc[4][dx], acc[5][dx], acc[6][dx], acc[7][dx]);
    }
  }
  __syncthreads();

  if (tid < 144) {  // sum 4 wave-partials, scale, store
    const int dx = tid >> 4, qq = tid & 15;
    const float s = 1.0f / 256.0f;
    float r[8];
#pragma unroll
    for (int px = 0; px < 8; ++px) r[px] = 0.0f;
#pragma unroll
    for (int w4 = 0; w4 < 4; ++w4) {
      const int pb = ((w4 * 16 + qq) * 9 + dx) * 8;
      const float4 lo = *(const float4*)&lds[pb];
      const float4 hi = *(const float4*)&lds[pb + 4];
      r[0] += lo.x; r[1] += lo.y; r[2] += lo.z; r[3] += lo.w;
      r[4] += hi.x; r[5] += hi.y; r[6] += hi.z; r[7] += hi.w;
    }
    *(float4*)(outbase + (size_t)dx * HW + 8 * qq) =
        make_float4(r[0] * s, r[1] * s, r[2] * s, r[3] * s);
    *(float4*)(outbase + (size_t)dx * HW + 8 * qq + 4) =
        make_float4(r[4] * s, r[5] * s, r[6] * s, r[7] * s);
  }
}

}  // namespace

extern "C" void kernel_launch(void* const* d_in, const int* in_sizes, int n_in,
                              void* d_out, int out_size, void* d_ws,
                              size_t ws_size, hipStream_t stream) {
  (void)in_sizes; (void)n_in; (void)out_size; (void)d_ws; (void)ws_size;
  const float* in1 = (const float*)d_in[0];
  const float* in2 = (const float*)d_in[1];
  float* outp = (float*)d_out;
  corr_kernel<<<4608, 256, 0, stream>>>(in1, in2, outp);
}

// Round 14
// 88.371 us; speedup vs baseline: 1.1951x; 1.0454x over previous
//
#include <hip/hip_runtime.h>

// FlowNetC correlation, B=8 C=256 H=64 W=128, 9x9 grid.
// out[b,dy*9+dx,h,w] = (1/256) * sum_c in1[b,c,h,w]*in2[b,c,h+dy-4,w+dx-4]
// (in2 zero-padded by 4 in h,w).
//
// Block = (b,h,dy) -> ONE in2 row. 4608 blocks x 256 thr (4 waves).
// Thread = (q:16 w-octs) x (cslo:4); wave w owns channels 16P+4w+{0..3}.
// R14 vs R13-92us (two levers, both from measured facts):
//  (a) v1 in REGISTERS again (R8-proven no-spill): LDS reads 6->4 b128/phase,
//      halves LDS write traffic. LDS-pipe arithmetic: 6 reads = ~41us/CU of
//      ds_read cycles + 13us conflicts -- co-dominant with the wait chain.
//  (b) in2 quad-buffer NBUF=4 at PBUF=520 -> 33.3 KB (SAME as R13) -> keeps
//      3 blocks/CU while S(p+2),S(p+3) ride through every compute. R11
//      showed depth-3 gives +36% per-wave throughput; this time occupancy
//      is not traded away. Counted FIFO: VMCNT(8) ph0, (6) steady, 4/2/0 tail.
//  (c) bank-conflict-free rotation: channel c row stored rotated by 4c
//      floats (src-side swizzle only; DMA dest linear per m104). Read banks
//      (8q+4cslo+d)&31 -> 8 lanes/4-bank slot = 8-cyc b128 floor.
// Falsified: DMA instr count (R8), line density (R10), per-wave depth at
// lost occupancy (R11), scatter (R12), staging mechanism (R13).
// Tripwires: WRITE_SIZE == 20736 KB; LGKM0 after COMPUTE (R9 race: next
// STAGE targets the buffer just read).

#define AS1 __attribute__((address_space(1)))
#define AS3 __attribute__((address_space(3)))

namespace {

constexpr int Cc = 256, Hh = 64, Ww = 128;
constexpr int HW = Hh * Ww;   // 8192
constexpr int ND = 81;
constexpr int PBUF = 520;     // per wave/buffer: 512 in2 + 4 zero + 4 pad
constexpr int NBUF = 4;
constexpr int WREG = NBUF * PBUF;  // 2080 floats per wave

__device__ __forceinline__ void async16(const float* g, float* l) {
  __builtin_amdgcn_global_load_lds((const AS1 unsigned int*)g,
                                   (AS3 unsigned int*)l, 16, 0, 0);
}

__global__ __launch_bounds__(256, 3) void corr_kernel(
    const float* __restrict__ in1, const float* __restrict__ in2,
    float* __restrict__ out) {
  __shared__ __align__(16) float lds[8320];  // 4 waves x 2080; reduce reuses [0,4608)

  const int tid = threadIdx.x;
  const int w = tid >> 6;
  const int lane = tid & 63;
  const int q = lane & 15;
  const int cslo = lane >> 4;

  // XCD swizzle: dispatch i -> XCD i%8; XCD x gets batch x; 9 dy-siblings of
  // one (b,h) are consecutive -> co-resident on one XCD, sharing rows in L2.
  const int bid0 = blockIdx.x;
  const int nb = (bid0 & 7) * 576 + (bid0 >> 3);
  const int b = nb / 576;
  const int rem = nb - b * 576;
  const int h = rem / 9;
  const int dy = rem - h * 9;
  const int row2 = h + dy - 4;

  float* outbase = out + (((size_t)b * ND + (size_t)dy * 9) * Hh + h) * Ww;

  if ((unsigned)row2 >= (unsigned)Hh) {  // dy shifts row out of range -> zeros
    if (tid < 144) {
      const int dx = tid >> 4, qq = tid & 15;
      const float4 z = make_float4(0.f, 0.f, 0.f, 0.f);
      *(float4*)(outbase + (size_t)dx * HW + 8 * qq) = z;
      *(float4*)(outbase + (size_t)dx * HW + 8 * qq + 4) = z;
    }
    return;
  }

  const int wb = w * WREG;
  // zero the 16-B zero-slot of each of the 4 buffers (floats 512..515)
  if (lane < 16) lds[wb + (lane >> 2) * PBUF + 512 + (lane & 3)] = 0.0f;

  // ---- in2 staging source (rotation pre-swizzle; DMA dest linear) ----
  // op covers 2 channel-rows; lane l -> local ch c, dest float 4l stores
  // src x = (4*(l&31) - 4*c) & 127 of channel row (4w + c).
  int srcA, srcB;
  {
    const int c0 = lane >> 5;            // 0,1  (op A)
    srcA = (4 * w + c0) * HW + ((4 * (lane & 31) - 4 * c0) & 127);
    const int c1 = 2 + (lane >> 5);      // 2,3  (op B)
    srcB = (4 * w + c1) * HW + ((4 * (lane & 31) - 4 * c1) & 127);
  }

  // ---- per-thread in2 window read offsets (channel cslo, rotated 4*cslo) ----
  // window t[k] = x 8q-4+k: quads d = -4,0,4,8; edges -> zero slot (512).
  const int ro0 =
      (q == 0) ? 512 : (128 * cslo + ((8 * q - 4 + 4 * cslo) & 127));
  const int ro1 = 128 * cslo + ((8 * q + 4 * cslo) & 127);
  const int ro2 = 128 * cslo + ((8 * q + 4 + 4 * cslo) & 127);
  const int ro3 =
      (q == 15) ? 512 : (128 * cslo + ((8 * q + 8 + 4 * cslo) & 127));

  const float* in2row = in2 + ((size_t)b * Cc * Hh + row2) * Ww;
  const float* v1p =
      in1 + ((size_t)(b * Cc + 4 * w + cslo) * Hh + h) * Ww + 8 * q;

#define STAGE(P, BI)                                                   \
  {                                                                    \
    const float* s2_ = in2row + (size_t)(16 * (P)) * HW;               \
    async16(s2_ + srcA, &lds[wb + (BI) * PBUF]);                       \
    async16(s2_ + srcB, &lds[wb + (BI) * PBUF + 256]);                 \
  }

#define LOADV1(P, DST)                                                 \
  {                                                                    \
    const float* pp_ = v1p + (size_t)(16 * (P)) * HW;                  \
    const float4 a_ = *(const float4*)pp_;                             \
    const float4 d_ = *(const float4*)(pp_ + 4);                       \
    DST[0] = a_.x; DST[1] = a_.y; DST[2] = a_.z; DST[3] = a_.w;        \
    DST[4] = d_.x; DST[5] = d_.y; DST[6] = d_.z; DST[7] = d_.w;        \
  }

#define COMPUTE(BI, V1)                                                  \
  {                                                                      \
    const int bb_ = wb + (BI) * PBUF;                                    \
    const float4 A_ = *(const float4*)&lds[bb_ + ro0]; /* t0..3  */      \
    const float4 B_ = *(const float4*)&lds[bb_ + ro1]; /* t4..7  */      \
    const float4 C_ = *(const float4*)&lds[bb_ + ro2]; /* t8..11 */      \
    const float4 D_ = *(const float4*)&lds[bb_ + ro3]; /* t12..15*/      \
    const float t_[16] = {A_.x, A_.y, A_.z, A_.w, B_.x, B_.y, B_.z, B_.w,\
                          C_.x, C_.y, C_.z, C_.w, D_.x, D_.y, D_.z, D_.w};\
    _Pragma("unroll") for (int dx_ = 0; dx_ < 9; ++dx_)                  \
      _Pragma("unroll") for (int px_ = 0; px_ < 8; ++px_)                \
        acc[px_][dx_] = fmaf(V1[px_], t_[px_ + dx_], acc[px_][dx_]);     \
  }

#define VMCNT(N) asm volatile("s_waitcnt vmcnt(" #N ")" ::: "memory")
// This wave's window ds_reads retired before its next-phase DMA overwrites
// the buffer just read (R9 race). sched_barrier pins codegen (rule #18).
#define LGKM0                                             \
  asm volatile("s_waitcnt lgkmcnt(0)" ::: "memory");      \
  __builtin_amdgcn_sched_barrier(0)

  float acc[8][9];
#pragma unroll
  for (int px = 0; px < 8; ++px)
#pragma unroll
    for (int dx = 0; dx < 9; ++dx) acc[px][dx] = 0.0f;

  float v1a[8], v1b[8];

  // Prologue FIFO: V1(0), S(0), S(1), S(2)  (8 ops)
  LOADV1(0, v1a);
  STAGE(0, 0); STAGE(1, 1); STAGE(2, 2);

  // Phase 0: issue V1(1), S(3) -> 12 outstanding; retire V1(0),S(0) -> keep 8
  LOADV1(1, v1b); STAGE(3, 3); VMCNT(8); COMPUTE(0, v1a); LGKM0;

  // Steady phases 1..12: issue V1(p+1), S(p+3); VMCNT(6) retires S(p),
  // S(p+1), V1(p); keeps S(p+2), V1(p+1), S(p+3) in flight.
#pragma unroll 1
  for (int pp = 1; pp <= 9; pp += 4) {
    LOADV1(pp + 1, v1a); STAGE(pp + 3, 0); VMCNT(6); COMPUTE(1, v1b); LGKM0;
    LOADV1(pp + 2, v1b); STAGE(pp + 4, 1); VMCNT(6); COMPUTE(2, v1a); LGKM0;
    LOADV1(pp + 3, v1a); STAGE(pp + 5, 2); VMCNT(6); COMPUTE(3, v1b); LGKM0;
    LOADV1(pp + 4, v1b); STAGE(pp + 6, 3); VMCNT(6); COMPUTE(0, v1a); LGKM0;
  }
  // Tail: phases 13,14,15 (S(13..15) already issued)
  LOADV1(14, v1a); VMCNT(4); COMPUTE(1, v1b); LGKM0;
  LOADV1(15, v1b); VMCNT(2); COMPUTE(2, v1a); LGKM0;
  VMCNT(0); COMPUTE(3, v1b);

  // reduce the 4 cslo slices within each wave (lanes q, q+16, q+32, q+48)
#pragma unroll
  for (int px = 0; px < 8; ++px)
#pragma unroll
    for (int dx = 0; dx < 9; ++dx) {
      float v = acc[px][dx];
      v += __shfl_xor(v, 16, 64);
      v += __shfl_xor(v, 32, 64);
      acc[px][dx] = v;
    }

  __syncthreads();  // all waves done with staging region before overwrite
  if (cslo == 0) {  // wave partial: lds[((w*16+q)*9+dx)*8+px]
    const int pb = (w * 16 + q) * 72;
#pragma unroll
    for (int dx = 0; dx < 9; ++dx) {
      *(float4*)&lds[pb + dx * 8] =
          make_float4(acc[0][dx], acc[1][dx], acc[2][dx], acc[3][dx]);
      *(float4*)&lds[pb + dx * 8 + 4] =
          make_float4(acc[4][dx], acc[5][dx], acc[6][dx], acc[7][dx]);
    }
  }
  __syncthreads();

  if (tid < 144) {  // sum 4 wave-partials, scale, store
    const int dx = tid >> 4, qq = tid & 15;
    const float s = 1.0f / 256.0f;
    float r[8];
#pragma unroll
    for (int px = 0; px < 8; ++px) r[px] = 0.0f;
#pragma unroll
    for (int w4 = 0; w4 < 4; ++w4) {
      const int pb = ((w4 * 16 + qq) * 9 + dx) * 8;
      const float4 lo = *(const float4*)&lds[pb];
      const float4 hi = *(const float4*)&lds[pb + 4];
      r[0] += lo.x; r[1] += lo.y; r[2] += lo.z; r[3] += lo.w;
      r[4] += hi.x; r[5] += hi.y; r[6] += hi.z; r[7] += hi.w;
    }
    *(float4*)(outbase + (size_t)dx * HW + 8 * qq) =
        make_float4(r[0] * s, r[1] * s, r[2] * s, r[3] * s);
    *(float4*)(outbase + (size_t)dx * HW + 8 * qq + 4) =
        make_float4(r[4] * s, r[5] * s, r[6] * s, r[7] * s);
  }
}

}  // namespace

extern "C" void kernel_launch(void* const* d_in, const int* in_sizes, int n_in,
                              void* d_out, int out_size, void* d_ws,
                              size_t ws_size, hipStream_t stream) {
  (void)in_sizes; (void)n_in; (void)out_size; (void)d_ws; (void)ws_size;
  const float* in1 = (const float*)d_in[0];
  const float* in2 = (const float*)d_in[1];
  float* outp = (float*)d_out;
  corr_kernel<<<4608, 256, 0, stream>>>(in1, in2, outp);
}